// Round 8
// baseline (580.229 us; speedup 1.0000x reference)
//
#include <hip/hip_runtime.h>
#include <cstdint>
#include <cstddef>

// Problem constants
#define Bn 16
#define Sn 2048
#define Hn 1024
#define Nn 2048   // n_examples * mem_len

typedef unsigned short u16;
typedef __bf16 bf16x8 __attribute__((ext_vector_type(8)));
typedef float  f32x4  __attribute__((ext_vector_type(4)));
typedef int    i32x4  __attribute__((ext_vector_type(4)));
typedef short  s16x8  __attribute__((ext_vector_type(8)));
typedef unsigned short u16x8 __attribute__((ext_vector_type(8)));
typedef unsigned int   u32x4 __attribute__((ext_vector_type(4)));
typedef unsigned char  u8x4  __attribute__((ext_vector_type(4)));
typedef unsigned char  u8x8  __attribute__((ext_vector_type(8)));

__device__ __forceinline__ u16 f2bf(float f) {        // RNE float->bf16
  unsigned u = __builtin_bit_cast(unsigned, f);
  u += 0x7fffu + ((u >> 16) & 1u);
  return (u16)(u >> 16);
}

__device__ __forceinline__ bf16x8 ldfrag(const void* p) {  // ds_read_b128
  u32x4 u = *(const u32x4*)p;
  return __builtin_bit_cast(bf16x8, u);
}

// Two-level int8 quantization: x ~ (q1 + q2/128)/16, q1,q2 in [-127,127].
__device__ __forceinline__ void quant2(float x, char& q1, char& q2) {
  float f1 = rintf(x * 16.f);
  f1 = fminf(127.f, fmaxf(-127.f, f1));
  float r = x - f1 * 0.0625f;
  float f2 = rintf(r * 2048.f);
  f2 = fminf(127.f, fmaxf(-127.f, f2));
  q1 = (char)(int)f1;
  q2 = (char)(int)f2;
}

// Stage 16 rows x 64B (one global_load_lds_dwordx4 per lane, LDS dest linear
// base + lane*16). Global source granule XOR-swizzled with (row>>1)&3 so the
// ds_read side (same XOR) is bank-conflict-free (both-sides rule #21).
__device__ __forceinline__ void stage64Bb(const char* gbase, int pitchBytes, void* ldsbase, int lane) {
  const int gsrc = (lane & 3) ^ ((lane >> 3) & 3);   // g ^ ((row_local>>1)&3), row_local = lane>>2
  const char* gp = gbase + (size_t)(lane >> 2) * pitchBytes + gsrc * 16;
  __builtin_amdgcn_global_load_lds(
      (__attribute__((address_space(1))) void*)gp,
      (__attribute__((address_space(3))) void*)ldsbase, 16, 0, 0);
}

// u16 variant (pitch in elements), same 64B-row swizzle.
__device__ __forceinline__ void stage64Bu(const u16* gbase, int pitchElems, void* ldsbase, int lane) {
  const int gsrc = (lane & 3) ^ ((lane >> 3) & 3);
  const u16* gp = gbase + (size_t)(lane >> 2) * pitchElems + gsrc * 8;
  __builtin_amdgcn_global_load_lds(
      (__attribute__((address_space(1))) void*)gp,
      (__attribute__((address_space(3))) void*)ldsbase, 16, 0, 0);
}

// ---------------- prep kernels (batch-chunk local) ----------------

// seq fp32 -> two-level i8, 4 per thread.
__global__ __launch_bounds__(256) void prep_seq_i8(const float* __restrict__ seq,
                                                   char* __restrict__ a1, char* __restrict__ a2) {
  size_t i = (size_t)blockIdx.x * 256 + threadIdx.x;
  float4 v = ((const float4*)seq)[i];
  float x[4] = {v.x, v.y, v.z, v.w};
  u8x4 p1, p2;
#pragma unroll
  for (int j = 0; j < 4; ++j) {
    char q1, q2;
    quant2(x[j], q1, q2);
    p1[j] = (unsigned char)q1;
    p2[j] = (unsigned char)q2;
  }
  ((u8x4*)a1)[i] = p1;
  ((u8x4*)a2)[i] = p2;
}

// Fused memory prep: reads each mem element ONCE (as the [N][H] view), emits
//  bt1[n'][h'] i8 two-level  where flat[h'*2048+n'] = flat[r*1024+c]
//    (n' = (r&1)*1024 + c, h' = r>>1; mask index = 2h'+(n'>>10) = r)
//  bt2[h][n]  bf16           (transpose of the natural [N][H] view; mask mk[n])
// Region per block: [N][H]-view rows r0..r0+63, cols c0..c0+31.
__global__ __launch_bounds__(256) void prep_bt(const float* __restrict__ mem,
                                               const int* __restrict__ mmask,
                                               char* __restrict__ b1o, char* __restrict__ b2o,
                                               u16* __restrict__ bt2) {
  __shared__ float tile[64][33];
  const int b = blockIdx.z;
  const int r0 = blockIdx.x * 64;   // 32 blocks
  const int c0 = blockIdx.y * 32;   // 32 blocks
  const int tx = threadIdx.x & 31, ty = threadIdx.x >> 5;   // 32 x 8
  const float* src = mem + (size_t)b * (Nn * Hn);
  const int* mk = mmask + b * Nn;
#pragma unroll
  for (int j = 0; j < 8; ++j) {
    int r = r0 + ty + j * 8;
    float v = src[(size_t)r * Hn + c0 + tx];
    v = mk[r] ? v : 0.f;
    tile[ty + j * 8][tx] = v;
  }
  __syncthreads();
  // bt2: h = c0 + hl (32 rows), n = r0 + n8*8 + j (64 cols); 8 bf16 per thread
  {
    const int hl = threadIdx.x & 31;
    const int n8 = threadIdx.x >> 5;
    u16x8 ov;
#pragma unroll
    for (int j = 0; j < 8; ++j) ov[j] = f2bf(tile[n8 * 8 + j][hl]);
    *(u16x8*)(bt2 + (size_t)b * Hn * Nn + (size_t)(c0 + hl) * Nn + r0 + n8 * 8) = ov;
  }
  // bt1: n' = p*1024 + c0 + cl, h' = r0/2 + q*8 + j; 8 i8 pairs per thread
  {
    const int cl = threadIdx.x & 31;
    const int p  = (threadIdx.x >> 5) & 1;
    const int q  = threadIdx.x >> 6;          // 0..3
    u8x8 o1, o2;
#pragma unroll
    for (int j = 0; j < 8; ++j) {
      char q1, q2;
      quant2(tile[2 * (q * 8 + j) + p][cl], q1, q2);
      o1[j] = (unsigned char)q1;
      o2[j] = (unsigned char)q2;
    }
    size_t o = (size_t)b * Nn * Hn + (size_t)(p * 1024 + c0 + cl) * Hn + (r0 >> 1) + q * 8;
    *(u8x8*)(b1o + o) = o1;
    *(u8x8*)(b2o + o) = o2;
  }
}

// ---------------- GEMM1: scores via two-level i8 split ----------------
// 128x256 tile, BK=64, 512 threads = 8 waves (2x4), wave-tile 64x64.
// THREE-deep LDS pipeline (3 x 48KB): stage(k+2) issued in iter k; barrier
// carries counted s_waitcnt vmcnt(6) so the freshly-issued stage stays in
// flight (only stage(k+1), issued a full iteration ago, must have landed).
// Output: i16 fixed-point scores x128.
__global__ __launch_bounds__(512, 2) void gemm_scores(
    const char* __restrict__ A1, const char* __restrict__ A2,
    const char* __restrict__ B1, const char* __restrict__ B2,
    short* __restrict__ C) {
  __shared__ __align__(16) char ldsm[147456];   // 3 x 48KB: [A1 8K|A2 8K|B1 16K|B2 16K]
  const int b = blockIdx.z;
  const int tn = blockIdx.x;   // 8  (one per XCD per dispatch round, round-robin)
  const int tm = blockIdx.y;   // 16
  const int tid = threadIdx.x;
  const int w = tid >> 6, l = tid & 63;
  const int wr = w >> 2, wc = w & 3;    // wave grid 2(M) x 4(N)
  const size_t aOff = (size_t)(b * Sn + tm * 128) * Hn;
  const size_t bOff = (size_t)(b * Nn + tn * 256) * Hn;

  i32x4 acc1[4][4] = {};
  i32x4 acc2[4][4] = {};

  // per-lane constant swizzled read offsets
  const int gRd = ((l >> 4) ^ ((l >> 1) & 3)) * 16;
  const int aoA = (wr * 64 + (l & 15)) * 64 + gRd;
  const int boB = (wc * 64 + (l & 15)) * 64 + gRd;

  // wave w stages rows w*96..w*96+95 of concat row-space [A1:128|A2:128|B1:256|B2:256]
  auto stageStep = [&](int kk, char* buf) {
    const int kb = kk * 64;
#pragma unroll
    for (int i = 0; i < 6; ++i) {
      const int r = w * 96 + i * 16;
      const char* src;
      if (r < 256) src = (r < 128 ? A1 + aOff + (size_t)r * Hn
                                  : A2 + aOff + (size_t)(r - 128) * Hn) + kb;
      else         src = (r < 512 ? B1 + bOff + (size_t)(r - 256) * Hn
                                  : B2 + bOff + (size_t)(r - 512) * Hn) + kb;
      stage64Bb(src, Hn, buf + r * 64, l);
    }
  };

  stageStep(0, ldsm);
  stageStep(1, ldsm + 49152);
  asm volatile("s_waitcnt vmcnt(6)" ::: "memory");
  __builtin_amdgcn_s_barrier();
  __builtin_amdgcn_sched_barrier(0);

  int cb = 0;
  for (int kk = 0; kk < 16; ++kk) {   // 16 K-steps of 64
    char* cur = ldsm + cb * 49152;
    int sb = cb + 2; if (sb >= 3) sb -= 3;
    if (kk + 2 < 16) stageStep(kk + 2, ldsm + sb * 49152);
    i32x4 a1c[4];
    // Pass 1: b1 x (a1 -> acc1, a2 -> acc2); a1 frags kept in regs
    {
      i32x4 bf[4];
#pragma unroll
      for (int ni = 0; ni < 4; ++ni) bf[ni] = *(const i32x4*)(cur + 16384 + boB + ni * 1024);
#pragma unroll
      for (int mi = 0; mi < 4; ++mi) {
        a1c[mi] = *(const i32x4*)(cur + aoA + mi * 1024);
      }
      i32x4 a2f[4];
#pragma unroll
      for (int mi = 0; mi < 4; ++mi) a2f[mi] = *(const i32x4*)(cur + 8192 + aoA + mi * 1024);
      __builtin_amdgcn_s_setprio(1);
#pragma unroll
      for (int mi = 0; mi < 4; ++mi)
#pragma unroll
        for (int ni = 0; ni < 4; ++ni) {
          acc1[mi][ni] = __builtin_amdgcn_mfma_i32_16x16x64_i8(a1c[mi], bf[ni], acc1[mi][ni], 0, 0, 0);
          acc2[mi][ni] = __builtin_amdgcn_mfma_i32_16x16x64_i8(a2f[mi], bf[ni], acc2[mi][ni], 0, 0, 0);
        }
      __builtin_amdgcn_s_setprio(0);
    }
    // Pass 2: b2 x cached a1 -> acc2
    {
      i32x4 bf[4];
#pragma unroll
      for (int ni = 0; ni < 4; ++ni) bf[ni] = *(const i32x4*)(cur + 32768 + boB + ni * 1024);
      __builtin_amdgcn_s_setprio(1);
#pragma unroll
      for (int mi = 0; mi < 4; ++mi)
#pragma unroll
        for (int ni = 0; ni < 4; ++ni)
          acc2[mi][ni] = __builtin_amdgcn_mfma_i32_16x16x64_i8(a1c[mi], bf[ni], acc2[mi][ni], 0, 0, 0);
      __builtin_amdgcn_s_setprio(0);
    }
    if (kk == 15) break;
    if (kk <= 13) asm volatile("s_waitcnt vmcnt(6)" ::: "memory");
    else          asm volatile("s_waitcnt vmcnt(0)" ::: "memory");
    __builtin_amdgcn_s_barrier();
    __builtin_amdgcn_sched_barrier(0);
    cb = (cb + 1 == 3) ? 0 : cb + 1;
  }
  // C/D frag: col = lane&15, row = (lane>>4)*4 + j
  // scores_fixed = (128*acc1 + acc2) / 256  (= true_score * 128), i16.
  const int r0 = tm * 128 + wr * 64 + (l >> 4) * 4;
  const int c0 = tn * 256 + wc * 64 + (l & 15);
#pragma unroll
  for (int mi = 0; mi < 4; ++mi)
#pragma unroll
    for (int ni = 0; ni < 4; ++ni) {
      size_t base = (size_t)(b * Sn + r0 + mi * 16) * Nn + c0 + ni * 16;
#pragma unroll
      for (int j = 0; j < 4; ++j) {
        int t = acc1[mi][ni][j] * 128 + acc2[mi][ni][j];
        int s = (int)rintf((float)t * (1.f / 256.f));
        s = s > 32767 ? 32767 : (s < -32767 ? -32767 : s);
        C[base + (size_t)j * Nn] = (short)s;
      }
    }
}

// ---------------- softmax over N on i16 scores (x128); bf16 probs in place ----------------
__global__ __launch_bounds__(256) void softmax_rows(short* __restrict__ sc) {
  __shared__ float red[8];
  const size_t row = blockIdx.x;
  short* p = sc + row * Nn;
  const int t = threadIdx.x;
  s16x8 v = ((const s16x8*)p)[t];
  float x[8];
#pragma unroll
  for (int j = 0; j < 8; ++j) x[j] = (float)v[j] * 0.0078125f;  // /128
  float m = x[0];
#pragma unroll
  for (int j = 1; j < 8; ++j) m = fmaxf(m, x[j]);
  for (int o = 32; o > 0; o >>= 1) m = fmaxf(m, __shfl_xor(m, o));
  if ((t & 63) == 0) red[t >> 6] = m;
  __syncthreads();
  m = fmaxf(fmaxf(red[0], red[1]), fmaxf(red[2], red[3]));
  float e[8], s = 0.f;
#pragma unroll
  for (int j = 0; j < 8; ++j) { e[j] = __expf(x[j] - m); s += e[j]; }
  for (int o = 32; o > 0; o >>= 1) s += __shfl_xor(s, o);
  if ((t & 63) == 0) red[4 + (t >> 6)] = s;
  __syncthreads();
  s = (red[4] + red[5]) + (red[6] + red[7]);
  const float inv = 1.f / s;
  u16x8 ob;
#pragma unroll
  for (int j = 0; j < 8; ++j) ob[j] = f2bf(e[j] * inv);
  ((u16x8*)p)[t] = ob;   // all reads of this row completed before last barrier
}

// ---------------- GEMM2: out = seq + probs @ mem, single bf16 ----------------
// 128x128 tile, BK=32, double-buffered LDS (2 x 16KB = 32KB total) -> 3
// blocks/CU (reg-capped). 16 MFMA + 8 ds_read per wave per K-step.
__global__ __launch_bounds__(256, 3) void gemm_attn(
    const u16* __restrict__ P,   // bf16 probs, row pitch 2048 elements
    const u16* __restrict__ Bt,  // Bt2 [BC][1024][2048]
    const float* __restrict__ seq, float* __restrict__ out) {
  __shared__ __align__(16) char ldsm[32768];   // 2 buffers x {AT 8KB, BT 8KB}
  const int b = blockIdx.z;
  // XCD remap: grid (8,16); each XCD gets a 4(tn) x 4(tm) rectangle.
  const int lid = blockIdx.x + (blockIdx.y << 3);
  const int xcd = lid & 7, idx = lid >> 3;
  const int tn = ((xcd & 1) << 2) | (idx & 3);
  const int tm = ((xcd >> 1) << 2) | (idx >> 2);
  const int tid = threadIdx.x;
  const int w = tid >> 6, l = tid & 63;
  const int wr = w >> 1, wc = w & 1;
  const size_t aOff = (size_t)(b * Sn + tm * 128) * Nn;   // P pitch 2048
  const size_t bOff = (size_t)(b * Hn + tn * 128) * Nn;

  f32x4 acc[4][4] = {};

  const int gRd = ((l >> 4) ^ ((l >> 1) & 3)) * 16;
  const int ao = (wr * 64 + (l & 15)) * 64 + gRd;
  const int bo = (wc * 64 + (l & 15)) * 64 + gRd;

  auto stageStep = [&](int kk, char* buf) {
    const int kb = kk * 32;
#pragma unroll
    for (int i = 0; i < 2; ++i) {
      const int rb = w * 32 + i * 16;
      stage64Bu(P + aOff + (size_t)rb * Nn + kb, Nn, buf + rb * 64, l);
      stage64Bu(Bt + bOff + (size_t)rb * Nn + kb, Nn, buf + 8192 + rb * 64, l);
    }
  };

  stageStep(0, ldsm);
  __syncthreads();

  for (int kk = 0; kk < Nn / 32; ++kk) {   // 64 K-steps
    char* cur = ldsm + (kk & 1) * 16384;
    if (kk < Nn / 32 - 1) stageStep(kk + 1, ldsm + ((kk + 1) & 1) * 16384);
    bf16x8 bfr[4];
#pragma unroll
    for (int ni = 0; ni < 4; ++ni) bfr[ni] = ldfrag(cur + 8192 + bo + ni * 1024);
    bf16x8 afr[4];
#pragma unroll
    for (int mi = 0; mi < 4; ++mi) afr[mi] = ldfrag(cur + ao + mi * 1024);
    __builtin_amdgcn_s_setprio(1);
#pragma unroll
    for (int mi = 0; mi < 4; ++mi)
#pragma unroll
      for (int ni = 0; ni < 4; ++ni)
        acc[mi][ni] = __builtin_amdgcn_mfma_f32_16x16x32_bf16(afr[mi], bfr[ni], acc[mi][ni], 0, 0, 0);
    __builtin_amdgcn_s_setprio(0);
    if (kk < Nn / 32 - 1) __syncthreads();
  }
  const int r0 = tm * 128 + wr * 64 + (l >> 4) * 4;
  const int c0 = tn * 128 + wc * 64 + (l & 15);
#pragma unroll
  for (int mi = 0; mi < 4; ++mi)
#pragma unroll
    for (int ni = 0; ni < 4; ++ni) {
      f32x4 v = acc[mi][ni];
      size_t base = (size_t)(b * Sn + r0 + mi * 16) * Hn + c0 + ni * 16;
      out[base] = seq[base] + v[0];
      out[base + Hn] = seq[base + Hn] + v[1];
      out[base + 2 * Hn] = seq[base + 2 * Hn] + v[2];
      out[base + 3 * Hn] = seq[base + 3 * Hn] + v[3];
    }
}

// Distinctive fill if ws is too small: absmax ~12345 tells us it was this guard.
__global__ void ws_fail(float* out) {
  size_t i = (size_t)blockIdx.x * blockDim.x + threadIdx.x;
  size_t stride = (size_t)gridDim.x * blockDim.x;
  for (; i < (size_t)Bn * Sn * Hn; i += stride) out[i] = 12345.0f;
}

extern "C" void kernel_launch(void* const* d_in, const int* in_sizes, int n_in,
                              void* d_out, int out_size, void* d_ws, size_t ws_size,
                              hipStream_t stream) {
  const float* seq = (const float*)d_in[0];
  // d_in[1] (attention_mask) is unused by the reference
  const float* mem = (const float*)d_in[2];
  const int* mmask = (const int*)d_in[3];
  float* out = (float*)d_out;

  // Per-batch: 4 x 2 MiB (i8 a1,a2,b1,b2) + 4 MiB bt2 + 8 MiB scores(i16) = 20 MiB
  const size_t MiB = 1024 * 1024;
  const size_t perB = 20 * MiB;
  int BC = 16;
  while (BC > 1 && (size_t)BC * perB > ws_size) BC >>= 1;
  if ((size_t)BC * perB > ws_size) {
    ws_fail<<<2048, 256, 0, stream>>>(out);
    return;
  }

  char* ws = (char*)d_ws;
  const size_t SEG8 = (size_t)BC * Sn * Hn;       // BC * 2 MiB (i8 arrays; Nn*Hn==Sn*Hn)
  char* a1 = ws;
  char* a2 = ws + SEG8;
  char* b1 = ws + 2 * SEG8;
  char* b2 = ws + 3 * SEG8;
  u16* bt2_hi = (u16*)(ws + 4 * SEG8);
  short* scores = (short*)(ws + 6 * SEG8);        // bt2 is 2*SEG8 bytes; scores 4*SEG8 bytes

  for (int b0 = 0; b0 < Bn; b0 += BC) {
    const float* seqb = seq + (size_t)b0 * Sn * Hn;
    const float* memb = mem + (size_t)b0 * Nn * Hn;
    const int* mkb = mmask + (size_t)b0 * Nn;
    float* outb = out + (size_t)b0 * Sn * Hn;

    prep_seq_i8<<<dim3(BC * Sn * Hn / 4 / 256), 256, 0, stream>>>(seqb, a1, a2);
    prep_bt<<<dim3(Nn / 64, Hn / 32, BC), 256, 0, stream>>>(memb, mkb, b1, b2, bt2_hi);
    gemm_scores<<<dim3(Nn / 256, Sn / 128, BC), 512, 0, stream>>>(a1, a2, b1, b2, scores);
    softmax_rows<<<dim3(BC * Sn), 256, 0, stream>>>(scores);
    gemm_attn<<<dim3(Hn / 128, Sn / 128, BC), 256, 0, stream>>>((const u16*)scores, bt2_hi, seqb, outb);
  }
}

// Round 9
// 485.510 us; speedup vs baseline: 1.1951x; 1.1951x over previous
//
#include <hip/hip_runtime.h>
#include <cstdint>
#include <cstddef>

// Problem constants
#define Bn 16
#define Sn 2048
#define Hn 1024
#define Nn 2048   // n_examples * mem_len

typedef unsigned short u16;
typedef __bf16 bf16x8 __attribute__((ext_vector_type(8)));
typedef float  f32x4  __attribute__((ext_vector_type(4)));
typedef int    i32x4  __attribute__((ext_vector_type(4)));
typedef short  s16x8  __attribute__((ext_vector_type(8)));
typedef unsigned short u16x8 __attribute__((ext_vector_type(8)));
typedef unsigned int   u32x4 __attribute__((ext_vector_type(4)));
typedef unsigned char  u8x4  __attribute__((ext_vector_type(4)));
typedef unsigned char  u8x8  __attribute__((ext_vector_type(8)));

__device__ __forceinline__ u16 f2bf(float f) {        // RNE float->bf16 (kept for reference)
  unsigned u = __builtin_bit_cast(unsigned, f);
  u += 0x7fffu + ((u >> 16) & 1u);
  return (u16)(u >> 16);
}

// Two-level int8 quantization: x ~ (q1 + q2/128)/16, q1,q2 in [-127,127].
__device__ __forceinline__ void quant2(float x, char& q1, char& q2) {
  float f1 = rintf(x * 16.f);
  f1 = fminf(127.f, fmaxf(-127.f, f1));
  float r = x - f1 * 0.0625f;
  float f2 = rintf(r * 2048.f);
  f2 = fminf(127.f, fmaxf(-127.f, f2));
  q1 = (char)(int)f1;
  q2 = (char)(int)f2;
}

// Single-level i8 x16 (for GEMM2's mem operand; max err 1/32).
__device__ __forceinline__ char quant1(float x) {
  float f = rintf(x * 16.f);
  f = fminf(127.f, fmaxf(-127.f, f));
  return (char)(int)f;
}

// Stage 16 rows x 64B (one global_load_lds_dwordx4 per lane, LDS dest linear
// base + lane*16). Global source granule XOR-swizzled with (row>>1)&3 so the
// ds_read side (same XOR) is bank-conflict-free (both-sides rule #21).
__device__ __forceinline__ void stage64Bb(const char* gbase, int pitchBytes, void* ldsbase, int lane) {
  const int gsrc = (lane & 3) ^ ((lane >> 3) & 3);   // g ^ ((row_local>>1)&3), row_local = lane>>2
  const char* gp = gbase + (size_t)(lane >> 2) * pitchBytes + gsrc * 16;
  __builtin_amdgcn_global_load_lds(
      (__attribute__((address_space(1))) void*)gp,
      (__attribute__((address_space(3))) void*)ldsbase, 16, 0, 0);
}

// ---------------- prep kernels (batch-chunk local) ----------------

// seq fp32 -> two-level i8, 4 per thread.
__global__ __launch_bounds__(256) void prep_seq_i8(const float* __restrict__ seq,
                                                   char* __restrict__ a1, char* __restrict__ a2) {
  size_t i = (size_t)blockIdx.x * 256 + threadIdx.x;
  float4 v = ((const float4*)seq)[i];
  float x[4] = {v.x, v.y, v.z, v.w};
  u8x4 p1, p2;
#pragma unroll
  for (int j = 0; j < 4; ++j) {
    char q1, q2;
    quant2(x[j], q1, q2);
    p1[j] = (unsigned char)q1;
    p2[j] = (unsigned char)q2;
  }
  ((u8x4*)a1)[i] = p1;
  ((u8x4*)a2)[i] = p2;
}

// Fused memory prep: reads each mem element ONCE (as the [N][H] view), emits
//  bt1[n'][h'] i8 two-level  where flat[h'*2048+n'] = flat[r*1024+c]
//    (n' = (r&1)*1024 + c, h' = r>>1; mask index = 2h'+(n'>>10) = r)
//  bt2[h][n]  i8 x16         (transpose of the natural [N][H] view; mask mk[n])
__global__ __launch_bounds__(256) void prep_bt(const float* __restrict__ mem,
                                               const int* __restrict__ mmask,
                                               char* __restrict__ b1o, char* __restrict__ b2o,
                                               char* __restrict__ bt2) {
  __shared__ float tile[64][33];
  const int b = blockIdx.z;
  const int r0 = blockIdx.x * 64;   // 32 blocks
  const int c0 = blockIdx.y * 32;   // 32 blocks
  const int tx = threadIdx.x & 31, ty = threadIdx.x >> 5;   // 32 x 8
  const float* src = mem + (size_t)b * (Nn * Hn);
  const int* mk = mmask + b * Nn;
#pragma unroll
  for (int j = 0; j < 8; ++j) {
    int r = r0 + ty + j * 8;
    float v = src[(size_t)r * Hn + c0 + tx];
    v = mk[r] ? v : 0.f;
    tile[ty + j * 8][tx] = v;
  }
  __syncthreads();
  // bt2: h = c0 + hl (32 rows), n = r0 + n8*8 + j (64 cols); 8 i8 per thread
  {
    const int hl = threadIdx.x & 31;
    const int n8 = threadIdx.x >> 5;
    u8x8 ov;
#pragma unroll
    for (int j = 0; j < 8; ++j) ov[j] = (unsigned char)quant1(tile[n8 * 8 + j][hl]);
    *(u8x8*)(bt2 + (size_t)b * Hn * Nn + (size_t)(c0 + hl) * Nn + r0 + n8 * 8) = ov;
  }
  // bt1: n' = p*1024 + c0 + cl, h' = r0/2 + q*8 + j; 8 i8 pairs per thread
  {
    const int cl = threadIdx.x & 31;
    const int p  = (threadIdx.x >> 5) & 1;
    const int q  = threadIdx.x >> 6;          // 0..3
    u8x8 o1, o2;
#pragma unroll
    for (int j = 0; j < 8; ++j) {
      char q1, q2;
      quant2(tile[2 * (q * 8 + j) + p][cl], q1, q2);
      o1[j] = (unsigned char)q1;
      o2[j] = (unsigned char)q2;
    }
    size_t o = (size_t)b * Nn * Hn + (size_t)(p * 1024 + c0 + cl) * Hn + (r0 >> 1) + q * 8;
    *(u8x8*)(b1o + o) = o1;
    *(u8x8*)(b2o + o) = o2;
  }
}

// ---------------- GEMM1: scores via two-level i8 split (R7 proven version) ----------------
// 128x128 tile, BK=64, 4 waves (2x2). Double-buffered LDS (2 x 32KB), one
// barrier per K-step. a1 frags cached in VGPR across both passes. i16 output.
__global__ __launch_bounds__(256, 2) void gemm_scores(
    const char* __restrict__ A1, const char* __restrict__ A2,
    const char* __restrict__ B1, const char* __restrict__ B2,
    short* __restrict__ C) {
  __shared__ __align__(16) char ldsm[65536];   // 2 buffers x {LA1,LA2,LB1,LB2} x 8KB
  const int b = blockIdx.z;
  // XCD-aware remap: each XCD's blocks form an 8(tn) x 4(tm) rectangle.
  const int lid = blockIdx.x + (blockIdx.y << 4);
  const int xcd = lid & 7, idx = lid >> 3;
  const int tn = ((xcd & 1) << 3) | (idx & 7);
  const int tm = ((xcd >> 1) << 2) | (idx >> 3);
  const int tid = threadIdx.x;
  const int w = tid >> 6, l = tid & 63;
  const int wr = w >> 1, wc = w & 1;
  const size_t aOff = (size_t)(b * Sn + tm * 128) * Hn;
  const size_t bOff = (size_t)(b * Nn + tn * 128) * Hn;

  i32x4 acc1[4][4] = {};
  i32x4 acc2[4][4] = {};

  const int gRd = ((l >> 4) ^ ((l >> 1) & 3)) * 16;
  const int ao = (wr * 64 + (l & 15)) * 64 + gRd;
  const int bo = (wc * 64 + (l & 15)) * 64 + gRd;

  auto stageStep = [&](int kk, char* buf) {
    const int kb = kk * 64;
#pragma unroll
    for (int i = 0; i < 2; ++i) {
      const int rb = w * 32 + i * 16;
      const size_t ro = (size_t)rb * Hn + kb;
      stage64Bb(A1 + aOff + ro, Hn, buf + rb * 64, l);
      stage64Bb(A2 + aOff + ro, Hn, buf + 8192 + rb * 64, l);
      stage64Bb(B1 + bOff + ro, Hn, buf + 16384 + rb * 64, l);
      stage64Bb(B2 + bOff + ro, Hn, buf + 24576 + rb * 64, l);
    }
  };

  stageStep(0, ldsm);
  __syncthreads();

  for (int kk = 0; kk < Hn / 64; ++kk) {   // 16 K-steps
    char* cur = ldsm + (kk & 1) * 32768;
    if (kk < Hn / 64 - 1) stageStep(kk + 1, ldsm + ((kk + 1) & 1) * 32768);
    i32x4 a1c[4];
    // Pass 1: b1 against a1 (->acc1) and a2 (->acc2); a1 kept in regs
    {
      i32x4 bf[4];
#pragma unroll
      for (int ni = 0; ni < 4; ++ni) bf[ni] = *(const i32x4*)(cur + 16384 + bo + ni * 1024);
#pragma unroll
      for (int mi = 0; mi < 4; ++mi) {
        a1c[mi] = *(const i32x4*)(cur + ao + mi * 1024);
        i32x4 a2f = *(const i32x4*)(cur + 8192 + ao + mi * 1024);
#pragma unroll
        for (int ni = 0; ni < 4; ++ni) {
          acc1[mi][ni] = __builtin_amdgcn_mfma_i32_16x16x64_i8(a1c[mi], bf[ni], acc1[mi][ni], 0, 0, 0);
          acc2[mi][ni] = __builtin_amdgcn_mfma_i32_16x16x64_i8(a2f, bf[ni], acc2[mi][ni], 0, 0, 0);
        }
      }
    }
    // Pass 2: b2 against cached a1 (->acc2)
    {
      i32x4 bf[4];
#pragma unroll
      for (int ni = 0; ni < 4; ++ni) bf[ni] = *(const i32x4*)(cur + 24576 + bo + ni * 1024);
#pragma unroll
      for (int mi = 0; mi < 4; ++mi)
#pragma unroll
        for (int ni = 0; ni < 4; ++ni)
          acc2[mi][ni] = __builtin_amdgcn_mfma_i32_16x16x64_i8(a1c[mi], bf[ni], acc2[mi][ni], 0, 0, 0);
    }
    if (kk < Hn / 64 - 1) __syncthreads();
  }
  // scores_fixed = (128*acc1 + acc2) / 256  (= true_score * 128), i16.
  const int r0 = tm * 128 + wr * 64 + (l >> 4) * 4;
  const int c0 = tn * 128 + wc * 64 + (l & 15);
#pragma unroll
  for (int mi = 0; mi < 4; ++mi)
#pragma unroll
    for (int ni = 0; ni < 4; ++ni) {
      size_t base = (size_t)(b * Sn + r0 + mi * 16) * Nn + c0 + ni * 16;
#pragma unroll
      for (int j = 0; j < 4; ++j) {
        int t = acc1[mi][ni][j] * 128 + acc2[mi][ni][j];
        int s = (int)rintf((float)t * (1.f / 256.f));
        s = s > 32767 ? 32767 : (s < -32767 ? -32767 : s);
        C[base + (size_t)j * Nn] = (short)s;
      }
    }
}

// ---------------- softmax over N on i16 scores (x128); u8 probs (x127) out ----------------
__global__ __launch_bounds__(256) void softmax_rows(const short* __restrict__ sc,
                                                    unsigned char* __restrict__ p8) {
  __shared__ float red[8];
  const size_t row = blockIdx.x;
  const short* p = sc + row * Nn;
  const int t = threadIdx.x;
  s16x8 v = ((const s16x8*)p)[t];
  float x[8];
#pragma unroll
  for (int j = 0; j < 8; ++j) x[j] = (float)v[j] * 0.0078125f;  // /128
  float m = x[0];
#pragma unroll
  for (int j = 1; j < 8; ++j) m = fmaxf(m, x[j]);
  for (int o = 32; o > 0; o >>= 1) m = fmaxf(m, __shfl_xor(m, o));
  if ((t & 63) == 0) red[t >> 6] = m;
  __syncthreads();
  m = fmaxf(fmaxf(red[0], red[1]), fmaxf(red[2], red[3]));
  float e[8], s = 0.f;
#pragma unroll
  for (int j = 0; j < 8; ++j) { e[j] = __expf(x[j] - m); s += e[j]; }
  for (int o = 32; o > 0; o >>= 1) s += __shfl_xor(s, o);
  if ((t & 63) == 0) red[4 + (t >> 6)] = s;
  __syncthreads();
  s = (red[4] + red[5]) + (red[6] + red[7]);
  const float inv = 127.f / s;
  u8x8 ob;
#pragma unroll
  for (int j = 0; j < 8; ++j) ob[j] = (unsigned char)(int)rintf(e[j] * inv);
  *(u8x8*)(p8 + row * Nn + t * 8) = ob;
}

// ---------------- GEMM2: out = seq + probs @ mem, single-level i8 ----------------
// 128x128 tile, BK=64 (i8 K=64/instr), dbuf 2 x 16KB = 32KB LDS, 3 blocks/CU.
// out = seq + acc / (127*16).
__global__ __launch_bounds__(256, 3) void gemm_attn(
    const char* __restrict__ P8,  // u8 probs x127, pitch 2048
    const char* __restrict__ Bt,  // i8 mem^T x16, [BC][1024][2048]
    const float* __restrict__ seq, float* __restrict__ out) {
  __shared__ __align__(16) char ldsm[32768];   // 2 buffers x {A 8KB, B 8KB}
  const int b = blockIdx.z;
  // XCD remap: grid (8,16); each XCD gets a 4(tn) x 4(tm) rectangle.
  const int lid = blockIdx.x + (blockIdx.y << 3);
  const int xcd = lid & 7, idx = lid >> 3;
  const int tn = ((xcd & 1) << 2) | (idx & 3);
  const int tm = ((xcd >> 1) << 2) | (idx >> 2);
  const int tid = threadIdx.x;
  const int w = tid >> 6, l = tid & 63;
  const int wr = w >> 1, wc = w & 1;
  const size_t aOff = (size_t)(b * Sn + tm * 128) * Nn;   // bytes, pitch 2048
  const size_t bOff = (size_t)(b * Hn + tn * 128) * Nn;

  i32x4 acc[4][4] = {};

  const int gRd = ((l >> 4) ^ ((l >> 1) & 3)) * 16;
  const int ao = (wr * 64 + (l & 15)) * 64 + gRd;
  const int bo = (wc * 64 + (l & 15)) * 64 + gRd;

  auto stageStep = [&](int kk, char* buf) {
    const int kb = kk * 64;
#pragma unroll
    for (int i = 0; i < 2; ++i) {
      const int rb = w * 32 + i * 16;
      stage64Bb(P8 + aOff + (size_t)rb * Nn + kb, Nn, buf + rb * 64, l);
      stage64Bb(Bt + bOff + (size_t)rb * Nn + kb, Nn, buf + 8192 + rb * 64, l);
    }
  };

  stageStep(0, ldsm);
  __syncthreads();

  for (int kk = 0; kk < Nn / 64; ++kk) {   // 32 K-steps
    char* cur = ldsm + (kk & 1) * 16384;
    if (kk < Nn / 64 - 1) stageStep(kk + 1, ldsm + ((kk + 1) & 1) * 16384);
    i32x4 bfr[4];
#pragma unroll
    for (int ni = 0; ni < 4; ++ni) bfr[ni] = *(const i32x4*)(cur + 8192 + bo + ni * 1024);
    i32x4 afr[4];
#pragma unroll
    for (int mi = 0; mi < 4; ++mi) afr[mi] = *(const i32x4*)(cur + ao + mi * 1024);
    __builtin_amdgcn_s_setprio(1);
#pragma unroll
    for (int mi = 0; mi < 4; ++mi)
#pragma unroll
      for (int ni = 0; ni < 4; ++ni)
        acc[mi][ni] = __builtin_amdgcn_mfma_i32_16x16x64_i8(afr[mi], bfr[ni], acc[mi][ni], 0, 0, 0);
    __builtin_amdgcn_s_setprio(0);
    if (kk < Nn / 64 - 1) __syncthreads();
  }
  const int r0 = tm * 128 + wr * 64 + (l >> 4) * 4;
  const int c0 = tn * 128 + wc * 64 + (l & 15);
  const float scl = 1.f / 2032.f;   // 1/(127*16)
#pragma unroll
  for (int mi = 0; mi < 4; ++mi)
#pragma unroll
    for (int ni = 0; ni < 4; ++ni) {
      size_t base = (size_t)(b * Sn + r0 + mi * 16) * Hn + c0 + ni * 16;
      out[base]          = seq[base]          + (float)acc[mi][ni][0] * scl;
      out[base + Hn]     = seq[base + Hn]     + (float)acc[mi][ni][1] * scl;
      out[base + 2 * Hn] = seq[base + 2 * Hn] + (float)acc[mi][ni][2] * scl;
      out[base + 3 * Hn] = seq[base + 3 * Hn] + (float)acc[mi][ni][3] * scl;
    }
}

// Distinctive fill if ws is too small: absmax ~12345 tells us it was this guard.
__global__ void ws_fail(float* out) {
  size_t i = (size_t)blockIdx.x * blockDim.x + threadIdx.x;
  size_t stride = (size_t)gridDim.x * blockDim.x;
  for (; i < (size_t)Bn * Sn * Hn; i += stride) out[i] = 12345.0f;
}

extern "C" void kernel_launch(void* const* d_in, const int* in_sizes, int n_in,
                              void* d_out, int out_size, void* d_ws, size_t ws_size,
                              hipStream_t stream) {
  const float* seq = (const float*)d_in[0];
  // d_in[1] (attention_mask) is unused by the reference
  const float* mem = (const float*)d_in[2];
  const int* mmask = (const int*)d_in[3];
  float* out = (float*)d_out;

  // Per-batch: a1,a2,b1,b2 (4x2 MiB) + bt2 i8 (2 MiB) + scores i16 (8 MiB) + p8 (4 MiB) = 22 MiB
  const size_t MiB = 1024 * 1024;
  const size_t perB = 22 * MiB;
  int BC = 16;
  while (BC > 1 && (size_t)BC * perB > ws_size) BC >>= 1;
  if ((size_t)BC * perB > ws_size) {
    ws_fail<<<2048, 256, 0, stream>>>(out);
    return;
  }

  char* ws = (char*)d_ws;
  const size_t SEG8 = (size_t)BC * Sn * Hn;       // BC * 2 MiB
  char* a1 = ws;
  char* a2 = ws + SEG8;
  char* b1 = ws + 2 * SEG8;
  char* b2 = ws + 3 * SEG8;
  char* bt2 = ws + 4 * SEG8;                      // 1 SEG8
  short* scores = (short*)(ws + 5 * SEG8);        // 4 SEG8 (BC x 8 MiB)
  unsigned char* p8 = (unsigned char*)(ws + 9 * SEG8);  // 2 SEG8 (BC x 4 MiB)

  for (int b0 = 0; b0 < Bn; b0 += BC) {
    const float* seqb = seq + (size_t)b0 * Sn * Hn;
    const float* memb = mem + (size_t)b0 * Nn * Hn;
    const int* mkb = mmask + (size_t)b0 * Nn;
    float* outb = out + (size_t)b0 * Sn * Hn;

    prep_seq_i8<<<dim3(BC * Sn * Hn / 4 / 256), 256, 0, stream>>>(seqb, a1, a2);
    prep_bt<<<dim3(Nn / 64, Hn / 32, BC), 256, 0, stream>>>(memb, mkb, b1, b2, bt2);
    gemm_scores<<<dim3(Nn / 128, Sn / 128, BC), 256, 0, stream>>>(a1, a2, b1, b2, scores);
    softmax_rows<<<dim3(BC * Sn), 256, 0, stream>>>(scores, p8);
    gemm_attn<<<dim3(Hn / 128, Sn / 128, BC), 256, 0, stream>>>((const char*)p8, bt2, seqb, outb);
  }
}